// Round 1
// baseline (280.851 us; speedup 1.0000x reference)
//
#include <hip/hip_runtime.h>

// PolynomialKernel: per row of 128 fp32 values:
//   x_norm = x / max(||x||_2, 1e-12)
//   out[0:128]    = x_norm
//   out[128:8384] = triu(i<=j) products x_norm[i]*x_norm[j] * degree_scales[1]
// Rows = B*L = 8192. Output row stride 8384 fp32.

#define DD 128
#define ROW_OUT (DD + DD * (DD + 1) / 2) /* 8384 */
#define NCHUNK (ROW_OUT / 4)             /* 2096 */

__global__ __launch_bounds__(256) void poly_kernel(
    const float* __restrict__ x, const float* __restrict__ scales,
    float* __restrict__ out) {
  __shared__ float s_x[DD];
  __shared__ float s_c1;
  __shared__ float s_c2;

  const int row = blockIdx.x;
  const int tid = threadIdx.x;
  const float* xr = x + (size_t)row * DD;

  // Stage row into LDS + sum of squares (threads 0..31 carry data).
  float partial = 0.0f;
  if (tid < 32) {
    float4 xv = ((const float4*)xr)[tid];
    ((float4*)s_x)[tid] = xv;
    partial = xv.x * xv.x + xv.y * xv.y + xv.z * xv.z + xv.w * xv.w;
  }
  if (tid < 64) {  // wave 0 reduction; lanes 32..63 contribute 0
#pragma unroll
    for (int off = 16; off >= 1; off >>= 1)
      partial += __shfl_down(partial, off, 64);
    if (tid == 0) {
      float nrm = sqrtf(partial);
      float inv = 1.0f / fmaxf(nrm, 1e-12f);
      s_c1 = inv;
      s_c2 = inv * inv * scales[1];
    }
  }
  __syncthreads();

  const float c1 = s_c1;
  const float c2 = s_c2;
  float* orow = out + (size_t)row * ROW_OUT;

  for (int p4 = tid; p4 < NCHUNK; p4 += 256) {
    const int p = p4 * 4;
    float4 v;
    if (p < DD) {
      float4 xv = ((const float4*)s_x)[p4];
      v = make_float4(xv.x * c1, xv.y * c1, xv.z * c1, xv.w * c1);
    } else {
      int k = p - DD;  // 0 .. 8255, 4-aligned
      // i = floor((257 - sqrt(257^2 - 8k)) / 2); radicand is a perfect
      // square (257-2i)^2 at row starts -> float sqrt exact there.
      float r = sqrtf((float)(257 * 257 - 8 * k));
      int i = (int)((257.0f - r) * 0.5f);
      int off = (i * (257 - i)) >> 1;
      if (off > k) {
        --i;
        off = (i * (257 - i)) >> 1;
      } else {
        int off2 = ((i + 1) * (256 - i)) >> 1;
        if (off2 <= k) {
          ++i;
          off = off2;
        }
      }
      int j = i + (k - off);
      float xi = s_x[i] * c2;
      float vv[4];
#pragma unroll
      for (int e = 0; e < 4; ++e) {
        if (j >= DD) {  // wrap to next triangle row
          ++i;
          j = i;
          xi = s_x[i] * c2;
        }
        vv[e] = xi * s_x[j];
        ++j;
      }
      v = make_float4(vv[0], vv[1], vv[2], vv[3]);
    }
    ((float4*)orow)[p4] = v;
  }
}

extern "C" void kernel_launch(void* const* d_in, const int* in_sizes, int n_in,
                              void* d_out, int out_size, void* d_ws,
                              size_t ws_size, hipStream_t stream) {
  const float* x = (const float*)d_in[0];
  const float* scales = (const float*)d_in[1];
  float* out = (float*)d_out;
  const int n_rows = in_sizes[0] / DD;  // 8192
  poly_kernel<<<n_rows, 256, 0, stream>>>(x, scales, out);
}